// Round 12
// baseline (514.673 us; speedup 1.0000x reference)
//
#include <hip/hip_runtime.h>
#include <math.h>

#define N_NODES 100000
#define N_EDGES 800000
#define DIM_IN 128
#define DIM_OUT 256
#define GRID 1024            // co-resident: 4 blocks/CU x 256 CUs (launch_bounds(512,8))
#define BLK 512              // 8 waves
#define GSZ (GRID * BLK)     // 524288 threads
#define NPB 64               // nodes per GEMM block
#define SCAN_BLKS 196        // ceil(100000 / 512)

typedef __bf16 bf16x8 __attribute__((ext_vector_type(8)));
typedef float  f32x4  __attribute__((ext_vector_type(4)));

// ---------------- init: zero counts | state(256) | bars(8) -----------------
__global__ __launch_bounds__(1024) void k_init(int* __restrict__ p) {
    int i = blockIdx.x * 1024 + threadIdx.x;
    if (i < N_NODES + 256 + 8) p[i] = 0;
}

// ---------------- helpers ---------------------------------------------------
__device__ __forceinline__ float bflo(unsigned u) {
    return __builtin_bit_cast(float, u << 16);
}
__device__ __forceinline__ float bfhi(unsigned u) {
    return __builtin_bit_cast(float, u & 0xffff0000u);
}
__device__ __forceinline__ float gelu_f(float h) {
    float u = h * h;
    float inner = h * (0.7978845608f + 0.0356774081f * u);
    float a = __builtin_amdgcn_exp2f(-2.8853900818f * __builtin_fabsf(inner));
    float t = (1.f - a) * __builtin_amdgcn_rcpf(1.f + a);
    t = __builtin_copysignf(t, inner);
    return 0.5f * h * (1.f + t);
}

// Software grid barrier (all GRID blocks co-resident by launch_bounds
// occupancy guarantee). Agent-scope acq_rel release/acquire gives cross-XCD
// visibility; proven correct in rounds 10-11 (absmax unchanged).
__device__ __forceinline__ void gbar(unsigned* bar) {
    __syncthreads();
    if (threadIdx.x == 0) {
        __hip_atomic_fetch_add(bar, 1u, __ATOMIC_ACQ_REL, __HIP_MEMORY_SCOPE_AGENT);
        while (__hip_atomic_load(bar, __ATOMIC_ACQUIRE, __HIP_MEMORY_SCOPE_AGENT)
               < (unsigned)GRID) {
            __builtin_amdgcn_s_sleep(2);
        }
    }
    __syncthreads();
}

// ---------------- mega kernel: cvt+count | scan | fill | agg ---------------
// NO MFMA phase here: launch_bounds(512,8) caps VGPR at 64 (agg needs ~40),
// which would catastrophically spill the GEMM working set (round-11 lesson).
__global__ __launch_bounds__(BLK, 8) void k_mega(
    const float* __restrict__ x, const float* __restrict__ W,
    const int* __restrict__ src, const int* __restrict__ dst,
    const float* __restrict__ deg_inv,
    unsigned short* __restrict__ xb, unsigned short* __restrict__ Wb,
    unsigned short* __restrict__ mb,
    int* __restrict__ counts, unsigned* __restrict__ state,
    unsigned* __restrict__ bars,
    int* __restrict__ incl, int* __restrict__ cursor, int* __restrict__ csr)
{
    __shared__ int ws8[8];
    __shared__ int sExc;

    const int tid  = threadIdx.x;
    const int bid  = blockIdx.x;
    const int gid  = bid * BLK + tid;
    const int lane = tid & 63;
    const int wid  = tid >> 6;

    // ===== Phase A: cvtX (f32->bf16 packed), cvtW, dst-count ===============
    for (int i = gid; i < N_NODES * DIM_IN / 4; i += GSZ) {
        const float4 v = reinterpret_cast<const float4*>(x)[i];
        unsigned short s0 = __builtin_bit_cast(unsigned short, (__bf16)v.x);
        unsigned short s1 = __builtin_bit_cast(unsigned short, (__bf16)v.y);
        unsigned short s2 = __builtin_bit_cast(unsigned short, (__bf16)v.z);
        unsigned short s3 = __builtin_bit_cast(unsigned short, (__bf16)v.w);
        uint2 o;
        o.x = (unsigned)s0 | ((unsigned)s1 << 16);
        o.y = (unsigned)s2 | ((unsigned)s3 << 16);
        reinterpret_cast<uint2*>(xb)[i] = o;
    }
    if (gid < DIM_IN * DIM_OUT)
        Wb[gid] = __builtin_bit_cast(unsigned short, (__bf16)W[gid]);
    for (int e = gid; e < N_EDGES; e += GSZ)
        atomicAdd(&counts[dst[e]], 1);
    gbar(bars + 0);

    // ===== Phase B: decoupled-lookback scan (512 nodes/block) ==============
    if (bid < SCAN_BLKS) {
        const int i = bid * BLK + tid;
        const int c = (i < N_NODES) ? counts[i] : 0;
        int v = c;
#pragma unroll
        for (int d2 = 1; d2 < 64; d2 <<= 1) {
            int t = __shfl_up(v, d2, 64);
            if (lane >= d2) v += t;
        }
        if (lane == 63) ws8[wid] = v;
        __syncthreads();
        if (wid == 0) {
            int s = (lane < 8) ? ws8[lane] : 0;
#pragma unroll
            for (int d2 = 1; d2 < 8; d2 <<= 1) {
                int t = __shfl_up(s, d2, 64);
                if (lane >= d2) s += t;
            }
            if (lane < 8) ws8[lane] = s;
        }
        __syncthreads();
        const int total = ws8[7];
        if (wid > 0) v += ws8[wid - 1];
        if (tid == 0 && bid > 0)
            __hip_atomic_store(&state[bid], (1u << 30) | (unsigned)total,
                               __ATOMIC_RELEASE, __HIP_MEMORY_SCOPE_AGENT);
        if (wid == 0) {
            int exclusive = 0;
            if (bid > 0) {
                int look = bid - 1;
                for (;;) {
                    int idx = look - lane;
                    unsigned s;
                    bool rdy;
                    do {
                        s = (idx >= 0) ? __hip_atomic_load(&state[idx], __ATOMIC_ACQUIRE,
                                                           __HIP_MEMORY_SCOPE_AGENT)
                                       : (2u << 30);
                        rdy = (s >> 30) != 0u;
                    } while (!__all(rdy));
                    unsigned long long incmask = __ballot((s >> 30) == 2u);
                    int firstInc = (incmask == 0ull) ? 64 : (__ffsll(incmask) - 1);
                    int contrib = (lane <= firstInc) ? (int)(s & 0x3FFFFFFFu) : 0;
#pragma unroll
                    for (int d2 = 32; d2 >= 1; d2 >>= 1)
                        contrib += __shfl_down(contrib, d2, 64);
                    contrib = __shfl(contrib, 0, 64);
                    exclusive += contrib;
                    if (firstInc < 64) break;
                    look -= 64;
                }
            }
            if (lane == 0) {
                sExc = exclusive;
                __hip_atomic_store(&state[bid],
                                   (2u << 30) | (unsigned)(exclusive + total),
                                   __ATOMIC_RELEASE, __HIP_MEMORY_SCOPE_AGENT);
            }
        }
        __syncthreads();
        v += sExc;
        if (i < N_NODES) {
            incl[i] = v;
            cursor[i] = v - c;
        }
    }
    gbar(bars + 1);

    // ===== Phase C: CSR fill ================================================
    for (int e = gid; e < N_EDGES; e += GSZ) {
        int pos = atomicAdd(&cursor[dst[e]], 1);
        csr[pos] = src[e];
    }
    gbar(bars + 2);

    // ===== Phase D: aggregate (wave per node, 8192 waves concurrent) =======
    // beg = incl[node-1] (CSR row start) -- no counts read needed.
    for (int node = bid * 8 + wid; node < N_NODES; node += GRID * 8) {
        int end = __builtin_amdgcn_readfirstlane(incl[node]);
        int beg = (node > 0) ? __builtin_amdgcn_readfirstlane(incl[node - 1]) : 0;
        float a0 = 0.f, a1 = 0.f, b0 = 0.f, b1 = 0.f;
        int e = beg;
        for (; e + 3 < end; e += 4) {
            int s0 = csr[e], s1 = csr[e + 1], s2 = csr[e + 2], s3 = csr[e + 3];
            unsigned u0 = reinterpret_cast<const unsigned*>(xb + (size_t)s0 * DIM_IN)[lane];
            unsigned u1 = reinterpret_cast<const unsigned*>(xb + (size_t)s1 * DIM_IN)[lane];
            unsigned u2 = reinterpret_cast<const unsigned*>(xb + (size_t)s2 * DIM_IN)[lane];
            unsigned u3 = reinterpret_cast<const unsigned*>(xb + (size_t)s3 * DIM_IN)[lane];
            a0 += bflo(u0) + bflo(u1);  a1 += bfhi(u0) + bfhi(u1);
            b0 += bflo(u2) + bflo(u3);  b1 += bfhi(u2) + bfhi(u3);
        }
        for (; e < end; ++e) {
            int s0 = csr[e];
            unsigned u0 = reinterpret_cast<const unsigned*>(xb + (size_t)s0 * DIM_IN)[lane];
            a0 += bflo(u0);
            a1 += bfhi(u0);
        }
        float d = deg_inv[node];
        float r0 = (a0 + b0) * d;
        float r1 = (a1 + b1) * d;
        unsigned short q0 = __builtin_bit_cast(unsigned short, (__bf16)r0);
        unsigned short q1 = __builtin_bit_cast(unsigned short, (__bf16)r1);
        reinterpret_cast<unsigned*>(mb + (size_t)node * DIM_IN)[lane] =
            (unsigned)q0 | ((unsigned)q1 << 16);
    }
}

// ---------------- MFMA GEMM + bias + GELU (own dispatch, full VGPR) --------
// 512 thr = 8 waves; block owns NPB=64 nodes in 2 sub-tiles of 32; wave w
// owns out cols [w*32, w*32+32). mfma(A=W_frag, B=m_frag): D col = node,
// row = out-within-16; lane's f32x4 = 4 consecutive out channels of one node.
__global__ __launch_bounds__(512, 4) void k_gemm(
    const unsigned short* __restrict__ mb,
    const unsigned short* __restrict__ Wb,
    const float* __restrict__ bias,
    float* __restrict__ out)
{
    const int wave = threadIdx.x >> 6;
    const int lane = threadIdx.x & 63;
    const int lr = lane & 15;
    const int kg = lane >> 4;
    const int o0 = wave * 32;
    const int nb0 = blockIdx.x * NPB;

    bf16x8 wfr[2][4];
#pragma unroll
    for (int mt = 0; mt < 2; ++mt)
#pragma unroll
        for (int ks = 0; ks < 4; ++ks)
            wfr[mt][ks] = *reinterpret_cast<const bf16x8*>(
                Wb + (size_t)(o0 + mt * 16 + lr) * DIM_IN + ks * 32 + kg * 8);

    f32x4 bias4[2];
#pragma unroll
    for (int mt = 0; mt < 2; ++mt)
        bias4[mt] = *reinterpret_cast<const f32x4*>(bias + o0 + mt * 16 + kg * 4);

#pragma unroll
    for (int st = 0; st < NPB / 32; ++st) {
        const int nb = nb0 + st * 32;
        if (nb >= N_NODES) break;

        bf16x8 mfr[2][4];
#pragma unroll
        for (int nt = 0; nt < 2; ++nt) {
            const unsigned short* brow = mb + (size_t)(nb + nt * 16 + lr) * DIM_IN;
#pragma unroll
            for (int ks = 0; ks < 4; ++ks)
                mfr[nt][ks] = *reinterpret_cast<const bf16x8*>(brow + ks * 32 + kg * 8);
        }

        f32x4 acc[2][2] = {};
#pragma unroll
        for (int ks = 0; ks < 4; ++ks)
#pragma unroll
            for (int mt = 0; mt < 2; ++mt)
#pragma unroll
                for (int nt = 0; nt < 2; ++nt)
                    acc[mt][nt] = __builtin_amdgcn_mfma_f32_16x16x32_bf16(
                        wfr[mt][ks], mfr[nt][ks], acc[mt][nt], 0, 0, 0);

#pragma unroll
        for (int nt = 0; nt < 2; ++nt) {
            const int node = nb + nt * 16 + lr;
            float* orow = out + (size_t)node * DIM_OUT + o0 + kg * 4;
#pragma unroll
            for (int mt = 0; mt < 2; ++mt) {
                f32x4 h = acc[mt][nt] + bias4[mt];
                f32x4 g;
                g[0] = gelu_f(h[0]);
                g[1] = gelu_f(h[1]);
                g[2] = gelu_f(h[2]);
                g[3] = gelu_f(h[3]);
                *reinterpret_cast<f32x4*>(orow + mt * 16) = g;
            }
        }
    }
}

extern "C" void kernel_launch(void* const* d_in, const int* in_sizes, int n_in,
                              void* d_out, int out_size, void* d_ws, size_t ws_size,
                              hipStream_t stream) {
    const float* x       = (const float*)d_in[0];
    const int*   ei      = (const int*)d_in[1];
    const float* deg_inv = (const float*)d_in[2];
    const float* W       = (const float*)d_in[3];
    const float* bias    = (const float*)d_in[4];
    float*       out     = (float*)d_out;

    const int* src = ei;
    const int* dst = ei + N_EDGES;

    // ws layout: mb | counts | state(256) | bars(8) | incl | cursor | csr | Wb | xb
    unsigned short* mb = (unsigned short*)d_ws;
    int*      counts = (int*)(mb + (size_t)N_NODES * DIM_IN);
    unsigned* state  = (unsigned*)(counts + N_NODES);
    unsigned* bars   = state + 256;
    int*      incl   = (int*)(bars + 8);
    int*      cursor = incl + N_NODES;
    int*      csr    = cursor + N_NODES;
    unsigned short* Wb = (unsigned short*)(csr + N_EDGES);
    unsigned short* xb = Wb + DIM_IN * DIM_OUT;

    k_init<<<(N_NODES + 256 + 8 + 1023) / 1024, 1024, 0, stream>>>(counts);
    k_mega<<<GRID, BLK, 0, stream>>>(x, W, src, dst, deg_inv,
                                     xb, Wb, mb, counts, state, bars,
                                     incl, cursor, csr);
    k_gemm<<<(N_NODES + NPB - 1) / NPB, 512, 0, stream>>>(mb, Wb, bias, out);
}

// Round 13
// 194.656 us; speedup vs baseline: 2.6440x; 2.6440x over previous
//
#include <hip/hip_runtime.h>
#include <math.h>

#define N_NODES 100000
#define N_EDGES 800000
#define DIM_IN 128
#define DIM_OUT 256
#define NPB 32     // nodes per GEMM block: 100000 = 3125 * 32 exactly
#define SCAN_NB 98 // ceil(100000/1024)

typedef __bf16 bf16x8 __attribute__((ext_vector_type(8)));
typedef float  f32x4  __attribute__((ext_vector_type(4)));

// ---------------- zero counts + lookback state -----------------------------
__global__ __launch_bounds__(1024) void k_zero(int* __restrict__ p) {
    int i = blockIdx.x * 1024 + threadIdx.x;
    if (i < N_NODES + 128) p[i] = 0;
}

// ---------------- count: dst histogram (critical path, minimal work) -------
__global__ __launch_bounds__(256) void k_count(const int* __restrict__ dst,
                                               int* __restrict__ counts) {
    int e = blockIdx.x * 256 + threadIdx.x;   // grid exact: 800000/256
    atomicAdd(&counts[dst[e]], 1);
}

// ---------------- single-dispatch decoupled-lookback scan ------------------
// 98 blocks x 1024 thr; all co-resident -> spin-wait safe. Proven r8-r10.
__global__ __launch_bounds__(1024) void k_scan(const int* __restrict__ counts,
                                               int* __restrict__ incl,
                                               int* __restrict__ cursor,
                                               unsigned* __restrict__ state) {
    __shared__ int ws[16];
    __shared__ int sExc;
    const int tid = threadIdx.x, lane = tid & 63, wid = tid >> 6;
    const int b = blockIdx.x;
    const int i = b * 1024 + tid;
    const int c = (i < N_NODES) ? counts[i] : 0;
    int v = c;
#pragma unroll
    for (int d = 1; d < 64; d <<= 1) {
        int t = __shfl_up(v, d, 64);
        if (lane >= d) v += t;
    }
    if (lane == 63) ws[wid] = v;
    __syncthreads();
    if (wid == 0) {
        int s = (lane < 16) ? ws[lane] : 0;
#pragma unroll
        for (int d = 1; d < 16; d <<= 1) {
            int t = __shfl_up(s, d, 64);
            if (lane >= d) s += t;
        }
        if (lane < 16) ws[lane] = s;
    }
    __syncthreads();
    const int total = ws[15];
    if (wid > 0) v += ws[wid - 1];
    if (tid == 0 && b > 0)
        __hip_atomic_store(&state[b], (1u << 30) | (unsigned)total,
                           __ATOMIC_RELEASE, __HIP_MEMORY_SCOPE_AGENT);
    if (wid == 0) {
        int exclusive = 0;
        if (b > 0) {
            int look = b - 1;
            for (;;) {
                int idx = look - lane;
                unsigned s;
                bool rdy;
                do {
                    s = (idx >= 0) ? __hip_atomic_load(&state[idx], __ATOMIC_ACQUIRE,
                                                       __HIP_MEMORY_SCOPE_AGENT)
                                   : (2u << 30);
                    rdy = (s >> 30) != 0u;
                } while (!__all(rdy));
                unsigned long long incmask = __ballot((s >> 30) == 2u);
                int firstInc = (incmask == 0ull) ? 64 : (__ffsll(incmask) - 1);
                int contrib = (lane <= firstInc) ? (int)(s & 0x3FFFFFFFu) : 0;
#pragma unroll
                for (int d = 32; d >= 1; d >>= 1) contrib += __shfl_down(contrib, d, 64);
                contrib = __shfl(contrib, 0, 64);
                exclusive += contrib;
                if (firstInc < 64) break;
                look -= 64;
            }
        }
        if (lane == 0) {
            sExc = exclusive;
            __hip_atomic_store(&state[b], (2u << 30) | (unsigned)(exclusive + total),
                               __ATOMIC_RELEASE, __HIP_MEMORY_SCOPE_AGENT);
        }
    }
    __syncthreads();
    v += sExc;
    if (i < N_NODES) {
        incl[i] = v;          // global inclusive scan
        cursor[i] = v - c;    // row start (exclusive)
    }
}

// ---------------- fill + cvtX + cvtW (fused: cvt streams under fill stalls) -
// grid exact: 12500 blocks x 256 = 3.2M threads = x float4 elements.
__global__ __launch_bounds__(256) void k_fillcvt(
    const float* __restrict__ x, const float* __restrict__ W,
    const int* __restrict__ src, const int* __restrict__ dst,
    int* __restrict__ cursor, int* __restrict__ csr,
    unsigned short* __restrict__ xb, unsigned short* __restrict__ Wb)
{
    int i = blockIdx.x * 256 + threadIdx.x;
    const float4 v = reinterpret_cast<const float4*>(x)[i];
    unsigned short s0 = __builtin_bit_cast(unsigned short, (__bf16)v.x);
    unsigned short s1 = __builtin_bit_cast(unsigned short, (__bf16)v.y);
    unsigned short s2 = __builtin_bit_cast(unsigned short, (__bf16)v.z);
    unsigned short s3 = __builtin_bit_cast(unsigned short, (__bf16)v.w);
    uint2 o;
    o.x = (unsigned)s0 | ((unsigned)s1 << 16);
    o.y = (unsigned)s2 | ((unsigned)s3 << 16);
    reinterpret_cast<uint2*>(xb)[i] = o;
    if (i < DIM_IN * DIM_OUT)
        Wb[i] = __builtin_bit_cast(unsigned short, (__bf16)W[i]);
    if (i < N_EDGES) {
        int pos = atomicAdd(&cursor[dst[i]], 1);
        csr[pos] = src[i];
    }
}

// ---------------- Aggregate: mb[n] = bf16(deg_inv[n] * sum xb[src]) --------
// One wave per node; lane holds one packed bf16x2 (4B) of the 256B row ->
// fully-coalesced read per edge. x8 unroll, 4 accumulator chains (proven r9).
__device__ __forceinline__ float bflo(unsigned u) {
    return __builtin_bit_cast(float, u << 16);
}
__device__ __forceinline__ float bfhi(unsigned u) {
    return __builtin_bit_cast(float, u & 0xffff0000u);
}

__global__ __launch_bounds__(256) void k_agg(const unsigned short* __restrict__ xb,
                                             const int* __restrict__ csr,
                                             const int* __restrict__ incl,
                                             const int* __restrict__ counts,
                                             const float* __restrict__ deg_inv,
                                             unsigned short* __restrict__ mb) {
    int wave = threadIdx.x >> 6;
    int lane = threadIdx.x & 63;
    int node = blockIdx.x * 4 + wave;        // grid exact: 25000*4
    int end = __builtin_amdgcn_readfirstlane(incl[node]);
    int beg = end - __builtin_amdgcn_readfirstlane(counts[node]);
    float a0 = 0.f, a1 = 0.f, b0 = 0.f, b1 = 0.f;
    float c0 = 0.f, c1 = 0.f, d0 = 0.f, d1 = 0.f;
    int e = beg;
    for (; e + 7 < end; e += 8) {
        int s0 = csr[e],     s1 = csr[e + 1], s2 = csr[e + 2], s3 = csr[e + 3];
        int s4 = csr[e + 4], s5 = csr[e + 5], s6 = csr[e + 6], s7 = csr[e + 7];
        unsigned u0 = reinterpret_cast<const unsigned*>(xb + (size_t)s0 * DIM_IN)[lane];
        unsigned u1 = reinterpret_cast<const unsigned*>(xb + (size_t)s1 * DIM_IN)[lane];
        unsigned u2 = reinterpret_cast<const unsigned*>(xb + (size_t)s2 * DIM_IN)[lane];
        unsigned u3 = reinterpret_cast<const unsigned*>(xb + (size_t)s3 * DIM_IN)[lane];
        unsigned u4 = reinterpret_cast<const unsigned*>(xb + (size_t)s4 * DIM_IN)[lane];
        unsigned u5 = reinterpret_cast<const unsigned*>(xb + (size_t)s5 * DIM_IN)[lane];
        unsigned u6 = reinterpret_cast<const unsigned*>(xb + (size_t)s6 * DIM_IN)[lane];
        unsigned u7 = reinterpret_cast<const unsigned*>(xb + (size_t)s7 * DIM_IN)[lane];
        a0 += bflo(u0) + bflo(u1);  a1 += bfhi(u0) + bfhi(u1);
        b0 += bflo(u2) + bflo(u3);  b1 += bfhi(u2) + bfhi(u3);
        c0 += bflo(u4) + bflo(u5);  c1 += bfhi(u4) + bfhi(u5);
        d0 += bflo(u6) + bflo(u7);  d1 += bfhi(u6) + bfhi(u7);
    }
    for (; e + 3 < end; e += 4) {
        int s0 = csr[e], s1 = csr[e + 1], s2 = csr[e + 2], s3 = csr[e + 3];
        unsigned u0 = reinterpret_cast<const unsigned*>(xb + (size_t)s0 * DIM_IN)[lane];
        unsigned u1 = reinterpret_cast<const unsigned*>(xb + (size_t)s1 * DIM_IN)[lane];
        unsigned u2 = reinterpret_cast<const unsigned*>(xb + (size_t)s2 * DIM_IN)[lane];
        unsigned u3 = reinterpret_cast<const unsigned*>(xb + (size_t)s3 * DIM_IN)[lane];
        a0 += bflo(u0) + bflo(u1);  a1 += bfhi(u0) + bfhi(u1);
        b0 += bflo(u2) + bflo(u3);  b1 += bfhi(u2) + bfhi(u3);
    }
    for (; e < end; ++e) {
        int s0 = csr[e];
        unsigned u0 = reinterpret_cast<const unsigned*>(xb + (size_t)s0 * DIM_IN)[lane];
        a0 += bflo(u0);
        a1 += bfhi(u0);
    }
    float d = deg_inv[node];
    float r0 = ((a0 + b0) + (c0 + d0)) * d;
    float r1 = ((a1 + b1) + (c1 + d1)) * d;
    unsigned short q0 = __builtin_bit_cast(unsigned short, (__bf16)r0);
    unsigned short q1 = __builtin_bit_cast(unsigned short, (__bf16)r1);
    reinterpret_cast<unsigned*>(mb + (size_t)node * DIM_IN)[lane] =
        (unsigned)q0 | ((unsigned)q1 << 16);
}

// ---------------- GELU (tanh form, branch-free) ----------------------------
__device__ __forceinline__ float gelu_f(float h) {
    float u = h * h;
    float inner = h * (0.7978845608f + 0.0356774081f * u);
    float a = __builtin_amdgcn_exp2f(-2.8853900818f * __builtin_fabsf(inner));
    float t = (1.f - a) * __builtin_amdgcn_rcpf(1.f + a);
    t = __builtin_copysignf(t, inner);
    return 0.5f * h * (1.f + t);
}

// ---------------- MFMA GEMM + bias + GELU (NPB=32, max store parallelism) --
// 512 thr = 8 waves; block owns 32 nodes (3125 blocks, 12/CU), wave w owns
// out cols [w*32, w*32+32). mfma(A=W_frag, B=m_frag): D col = lane&15 = node,
// row = kg*4+reg = out-within-16; lane's f32x4 = 4 consecutive out channels
// of one node -> plain float4 stores. No bounds checks (100000 % 32 == 0).
__global__ __launch_bounds__(512, 4) void k_gemm(
    const unsigned short* __restrict__ mb,
    const unsigned short* __restrict__ Wb,
    const float* __restrict__ bias,
    float* __restrict__ out)
{
    const int wave = threadIdx.x >> 6;
    const int lane = threadIdx.x & 63;
    const int lr = lane & 15;
    const int kg = lane >> 4;
    const int o0 = wave * 32;
    const int nb = blockIdx.x * NPB;

    bf16x8 wfr[2][4];
#pragma unroll
    for (int mt = 0; mt < 2; ++mt)
#pragma unroll
        for (int ks = 0; ks < 4; ++ks)
            wfr[mt][ks] = *reinterpret_cast<const bf16x8*>(
                Wb + (size_t)(o0 + mt * 16 + lr) * DIM_IN + ks * 32 + kg * 8);

    f32x4 bias4[2];
#pragma unroll
    for (int mt = 0; mt < 2; ++mt)
        bias4[mt] = *reinterpret_cast<const f32x4*>(bias + o0 + mt * 16 + kg * 4);

    bf16x8 mfr[2][4];
#pragma unroll
    for (int nt = 0; nt < 2; ++nt) {
        const unsigned short* brow = mb + (size_t)(nb + nt * 16 + lr) * DIM_IN;
#pragma unroll
        for (int ks = 0; ks < 4; ++ks)
            mfr[nt][ks] = *reinterpret_cast<const bf16x8*>(brow + ks * 32 + kg * 8);
    }

    f32x4 acc[2][2] = {};
#pragma unroll
    for (int ks = 0; ks < 4; ++ks)
#pragma unroll
        for (int mt = 0; mt < 2; ++mt)
#pragma unroll
            for (int nt = 0; nt < 2; ++nt)
                acc[mt][nt] = __builtin_amdgcn_mfma_f32_16x16x32_bf16(
                    wfr[mt][ks], mfr[nt][ks], acc[mt][nt], 0, 0, 0);

#pragma unroll
    for (int nt = 0; nt < 2; ++nt) {
        const int node = nb + nt * 16 + lr;
        float* orow = out + (size_t)node * DIM_OUT + o0 + kg * 4;
#pragma unroll
        for (int mt = 0; mt < 2; ++mt) {
            f32x4 h = acc[mt][nt] + bias4[mt];
            f32x4 g;
            g[0] = gelu_f(h[0]);
            g[1] = gelu_f(h[1]);
            g[2] = gelu_f(h[2]);
            g[3] = gelu_f(h[3]);
            *reinterpret_cast<f32x4*>(orow + mt * 16) = g;
        }
    }
}

extern "C" void kernel_launch(void* const* d_in, const int* in_sizes, int n_in,
                              void* d_out, int out_size, void* d_ws, size_t ws_size,
                              hipStream_t stream) {
    const float* x       = (const float*)d_in[0];
    const int*   ei      = (const int*)d_in[1];
    const float* deg_inv = (const float*)d_in[2];
    const float* W       = (const float*)d_in[3];
    const float* bias    = (const float*)d_in[4];
    float*       out     = (float*)d_out;

    const int* src = ei;
    const int* dst = ei + N_EDGES;

    // ws layout: mb | counts | state(128) | incl | cursor | csr | Wb | xb
    unsigned short* mb = (unsigned short*)d_ws;
    size_t mb_bytes = (size_t)N_NODES * DIM_IN * sizeof(unsigned short);   // 25.6 MB
    int*      counts = (int*)((char*)d_ws + mb_bytes);
    unsigned* state  = (unsigned*)(counts + N_NODES);
    int*      incl   = (int*)(state + 128);
    int*      cursor = incl + N_NODES;
    int*      csr    = cursor + N_NODES;
    unsigned short* Wb = (unsigned short*)(csr + N_EDGES);
    unsigned short* xb = Wb + DIM_IN * DIM_OUT;

    k_zero   <<<SCAN_NB, 1024, 0, stream>>>(counts);              // counts + state
    k_count  <<<N_EDGES / 256, 256, 0, stream>>>(dst, counts);
    k_scan   <<<SCAN_NB, 1024, 0, stream>>>(counts, incl, cursor, state);
    k_fillcvt<<<(N_NODES * DIM_IN / 4) / 256, 256, 0, stream>>>(x, W, src, dst,
                                                                cursor, csr, xb, Wb);
    k_agg    <<<N_NODES / 4, 256, 0, stream>>>(xb, csr, incl, counts, deg_inv, mb);
    k_gemm   <<<N_NODES / NPB, 512, 0, stream>>>(mb, Wb, bias, out);
}

// Round 14
// 191.335 us; speedup vs baseline: 2.6899x; 1.0174x over previous
//
#include <hip/hip_runtime.h>
#include <math.h>

#define N_NODES 100000
#define N_EDGES 800000
#define DIM_IN 128
#define DIM_OUT 256
#define NPB 64     // nodes per GEMM block: 2 sub-tiles of 32 (round-10 proven)
#define SCAN_NB 98 // ceil(100000/1024)

typedef __bf16 bf16x8 __attribute__((ext_vector_type(8)));
typedef float  f32x4  __attribute__((ext_vector_type(4)));

// ---------------- zero counts + lookback state -----------------------------
__global__ __launch_bounds__(1024) void k_zero(int* __restrict__ p) {
    int i = blockIdx.x * 1024 + threadIdx.x;
    if (i < N_NODES + 128) p[i] = 0;
}

// ---------------- prep: cvtX + cvtW + dst-count ----------------------------
// grid exact: 12500*256 = 3.2M threads = x float4 elements.
__global__ __launch_bounds__(256) void k_prep(const float* __restrict__ x,
                                              const float* __restrict__ W,
                                              const int* __restrict__ dst,
                                              unsigned short* __restrict__ xb,
                                              unsigned short* __restrict__ Wb,
                                              int* __restrict__ counts) {
    int i = blockIdx.x * 256 + threadIdx.x;
    const float4 v = reinterpret_cast<const float4*>(x)[i];
    unsigned short s0 = __builtin_bit_cast(unsigned short, (__bf16)v.x);
    unsigned short s1 = __builtin_bit_cast(unsigned short, (__bf16)v.y);
    unsigned short s2 = __builtin_bit_cast(unsigned short, (__bf16)v.z);
    unsigned short s3 = __builtin_bit_cast(unsigned short, (__bf16)v.w);
    uint2 o;
    o.x = (unsigned)s0 | ((unsigned)s1 << 16);
    o.y = (unsigned)s2 | ((unsigned)s3 << 16);
    reinterpret_cast<uint2*>(xb)[i] = o;
    if (i < DIM_IN * DIM_OUT) Wb[i] = __builtin_bit_cast(unsigned short, (__bf16)W[i]);
    if (i < N_EDGES) atomicAdd(&counts[dst[i]], 1);
}

// ---------------- single-dispatch decoupled-lookback scan (proven) ---------
__global__ __launch_bounds__(1024) void k_scan(const int* __restrict__ counts,
                                               int* __restrict__ incl,
                                               int* __restrict__ cursor,
                                               unsigned* __restrict__ state) {
    __shared__ int ws[16];
    __shared__ int sExc;
    const int tid = threadIdx.x, lane = tid & 63, wid = tid >> 6;
    const int b = blockIdx.x;
    const int i = b * 1024 + tid;
    const int c = (i < N_NODES) ? counts[i] : 0;
    int v = c;
#pragma unroll
    for (int d = 1; d < 64; d <<= 1) {
        int t = __shfl_up(v, d, 64);
        if (lane >= d) v += t;
    }
    if (lane == 63) ws[wid] = v;
    __syncthreads();
    if (wid == 0) {
        int s = (lane < 16) ? ws[lane] : 0;
#pragma unroll
        for (int d = 1; d < 16; d <<= 1) {
            int t = __shfl_up(s, d, 64);
            if (lane >= d) s += t;
        }
        if (lane < 16) ws[lane] = s;
    }
    __syncthreads();
    const int total = ws[15];
    if (wid > 0) v += ws[wid - 1];
    if (tid == 0 && b > 0)
        __hip_atomic_store(&state[b], (1u << 30) | (unsigned)total,
                           __ATOMIC_RELEASE, __HIP_MEMORY_SCOPE_AGENT);
    if (wid == 0) {
        int exclusive = 0;
        if (b > 0) {
            int look = b - 1;
            for (;;) {
                int idx = look - lane;
                unsigned s;
                bool rdy;
                do {
                    s = (idx >= 0) ? __hip_atomic_load(&state[idx], __ATOMIC_ACQUIRE,
                                                       __HIP_MEMORY_SCOPE_AGENT)
                                   : (2u << 30);
                    rdy = (s >> 30) != 0u;
                } while (!__all(rdy));
                unsigned long long incmask = __ballot((s >> 30) == 2u);
                int firstInc = (incmask == 0ull) ? 64 : (__ffsll(incmask) - 1);
                int contrib = (lane <= firstInc) ? (int)(s & 0x3FFFFFFFu) : 0;
#pragma unroll
                for (int d = 32; d >= 1; d >>= 1) contrib += __shfl_down(contrib, d, 64);
                contrib = __shfl(contrib, 0, 64);
                exclusive += contrib;
                if (firstInc < 64) break;
                look -= 64;
            }
        }
        if (lane == 0) {
            sExc = exclusive;
            __hip_atomic_store(&state[b], (2u << 30) | (unsigned)(exclusive + total),
                               __ATOMIC_RELEASE, __HIP_MEMORY_SCOPE_AGENT);
        }
    }
    __syncthreads();
    v += sExc;
    if (i < N_NODES) {
        incl[i] = v;
        cursor[i] = v - c;
    }
}

__global__ __launch_bounds__(256) void k_fill(const int* __restrict__ src,
                                              const int* __restrict__ dst,
                                              int* __restrict__ cursor,
                                              int* __restrict__ csr) {
    int e = blockIdx.x * 256 + threadIdx.x;   // grid exact: 800000/256
    int pos = atomicAdd(&cursor[dst[e]], 1);
    csr[pos] = src[e];
}

// ---------------- Aggregate: 4 edges per load instruction ------------------
// One wave per node. lane = (sub = lane>>4 edge-slot, part = lane&15 chunk):
// one uint4 (16B) load gathers edge sub's row-chunk part -> a wave instruction
// moves 4 full 256B rows. x2 unroll = 8 edges (2KB) in flight / 2 instrs.
// Epilogue: shfl_xor(16,32) reduces edge-slots; lanes 0-15 store the row.
__device__ __forceinline__ float bflo(unsigned u) {
    return __builtin_bit_cast(float, u << 16);
}
__device__ __forceinline__ float bfhi(unsigned u) {
    return __builtin_bit_cast(float, u & 0xffff0000u);
}

__global__ __launch_bounds__(256) void k_agg(const unsigned short* __restrict__ xb,
                                             const int* __restrict__ csr,
                                             const int* __restrict__ incl,
                                             const int* __restrict__ counts,
                                             const float* __restrict__ deg_inv,
                                             unsigned short* __restrict__ mb) {
    const int wave = threadIdx.x >> 6;
    const int lane = threadIdx.x & 63;
    const int node = blockIdx.x * 4 + wave;   // grid exact: 25000*4
    const int end = __builtin_amdgcn_readfirstlane(incl[node]);
    const int beg = end - __builtin_amdgcn_readfirstlane(counts[node]);
    const int cnt = end - beg;
    const int sub  = lane >> 4;   // edge slot 0..3
    const int part = lane & 15;   // 16B chunk of the 256B row

    float a0 = 0.f, a1 = 0.f, a2 = 0.f, a3 = 0.f;
    float a4 = 0.f, a5 = 0.f, a6 = 0.f, a7 = 0.f;

    int e = 0;
    for (; e + 8 <= cnt; e += 8) {
        int i0 = csr[beg + e + sub];
        int i1 = csr[beg + e + 4 + sub];
        uint4 u0 = *reinterpret_cast<const uint4*>(xb + (size_t)i0 * DIM_IN + part * 8);
        uint4 u1 = *reinterpret_cast<const uint4*>(xb + (size_t)i1 * DIM_IN + part * 8);
        a0 += bflo(u0.x) + bflo(u1.x);  a1 += bfhi(u0.x) + bfhi(u1.x);
        a2 += bflo(u0.y) + bflo(u1.y);  a3 += bfhi(u0.y) + bfhi(u1.y);
        a4 += bflo(u0.z) + bflo(u1.z);  a5 += bfhi(u0.z) + bfhi(u1.z);
        a6 += bflo(u0.w) + bflo(u1.w);  a7 += bfhi(u0.w) + bfhi(u1.w);
    }
    for (; e < cnt; e += 4) {
        if (e + sub < cnt) {
            int i0 = csr[beg + e + sub];
            uint4 u0 = *reinterpret_cast<const uint4*>(xb + (size_t)i0 * DIM_IN + part * 8);
            a0 += bflo(u0.x);  a1 += bfhi(u0.x);
            a2 += bflo(u0.y);  a3 += bfhi(u0.y);
            a4 += bflo(u0.z);  a5 += bfhi(u0.z);
            a6 += bflo(u0.w);  a7 += bfhi(u0.w);
        }
    }

    // reduce across the 4 edge-slots (lanes p, p+16, p+32, p+48)
#pragma unroll
    for (int m = 16; m <= 32; m <<= 1) {
        a0 += __shfl_xor(a0, m, 64);  a1 += __shfl_xor(a1, m, 64);
        a2 += __shfl_xor(a2, m, 64);  a3 += __shfl_xor(a3, m, 64);
        a4 += __shfl_xor(a4, m, 64);  a5 += __shfl_xor(a5, m, 64);
        a6 += __shfl_xor(a6, m, 64);  a7 += __shfl_xor(a7, m, 64);
    }

    if (lane < 16) {
        const float d = deg_inv[node];
        unsigned short q0 = __builtin_bit_cast(unsigned short, (__bf16)(a0 * d));
        unsigned short q1 = __builtin_bit_cast(unsigned short, (__bf16)(a1 * d));
        unsigned short q2 = __builtin_bit_cast(unsigned short, (__bf16)(a2 * d));
        unsigned short q3 = __builtin_bit_cast(unsigned short, (__bf16)(a3 * d));
        unsigned short q4 = __builtin_bit_cast(unsigned short, (__bf16)(a4 * d));
        unsigned short q5 = __builtin_bit_cast(unsigned short, (__bf16)(a5 * d));
        unsigned short q6 = __builtin_bit_cast(unsigned short, (__bf16)(a6 * d));
        unsigned short q7 = __builtin_bit_cast(unsigned short, (__bf16)(a7 * d));
        uint4 o;
        o.x = (unsigned)q0 | ((unsigned)q1 << 16);
        o.y = (unsigned)q2 | ((unsigned)q3 << 16);
        o.z = (unsigned)q4 | ((unsigned)q5 << 16);
        o.w = (unsigned)q6 | ((unsigned)q7 << 16);
        *reinterpret_cast<uint4*>(mb + (size_t)node * DIM_IN + part * 8) = o;
    }
}

// ---------------- GELU (tanh form, branch-free) ----------------------------
__device__ __forceinline__ float gelu_f(float h) {
    float u = h * h;
    float inner = h * (0.7978845608f + 0.0356774081f * u);
    float a = __builtin_amdgcn_exp2f(-2.8853900818f * __builtin_fabsf(inner));
    float t = (1.f - a) * __builtin_amdgcn_rcpf(1.f + a);
    t = __builtin_copysignf(t, inner);
    return 0.5f * h * (1.f + t);
}

// ---------------- MFMA GEMM + bias + GELU (round-10 proven, NPB=64) --------
__global__ __launch_bounds__(512, 4) void k_gemm(
    const unsigned short* __restrict__ mb,
    const unsigned short* __restrict__ Wb,
    const float* __restrict__ bias,
    float* __restrict__ out)
{
    const int wave = threadIdx.x >> 6;
    const int lane = threadIdx.x & 63;
    const int lr = lane & 15;
    const int kg = lane >> 4;
    const int o0 = wave * 32;
    const int nb0 = blockIdx.x * NPB;

    bf16x8 wfr[2][4];
#pragma unroll
    for (int mt = 0; mt < 2; ++mt)
#pragma unroll
        for (int ks = 0; ks < 4; ++ks)
            wfr[mt][ks] = *reinterpret_cast<const bf16x8*>(
                Wb + (size_t)(o0 + mt * 16 + lr) * DIM_IN + ks * 32 + kg * 8);

    f32x4 bias4[2];
#pragma unroll
    for (int mt = 0; mt < 2; ++mt)
        bias4[mt] = *reinterpret_cast<const f32x4*>(bias + o0 + mt * 16 + kg * 4);

#pragma unroll
    for (int st = 0; st < NPB / 32; ++st) {
        const int nb = nb0 + st * 32;
        if (nb >= N_NODES) break;

        bf16x8 mfr[2][4];
#pragma unroll
        for (int nt = 0; nt < 2; ++nt) {
            const unsigned short* brow = mb + (size_t)(nb + nt * 16 + lr) * DIM_IN;
#pragma unroll
            for (int ks = 0; ks < 4; ++ks)
                mfr[nt][ks] = *reinterpret_cast<const bf16x8*>(brow + ks * 32 + kg * 8);
        }

        f32x4 acc[2][2] = {};
#pragma unroll
        for (int ks = 0; ks < 4; ++ks)
#pragma unroll
            for (int mt = 0; mt < 2; ++mt)
#pragma unroll
                for (int nt = 0; nt < 2; ++nt)
                    acc[mt][nt] = __builtin_amdgcn_mfma_f32_16x16x32_bf16(
                        wfr[mt][ks], mfr[nt][ks], acc[mt][nt], 0, 0, 0);

#pragma unroll
        for (int nt = 0; nt < 2; ++nt) {
            const int node = nb + nt * 16 + lr;
            float* orow = out + (size_t)node * DIM_OUT + o0 + kg * 4;
#pragma unroll
            for (int mt = 0; mt < 2; ++mt) {
                f32x4 h = acc[mt][nt] + bias4[mt];
                f32x4 g;
                g[0] = gelu_f(h[0]);
                g[1] = gelu_f(h[1]);
                g[2] = gelu_f(h[2]);
                g[3] = gelu_f(h[3]);
                *reinterpret_cast<f32x4*>(orow + mt * 16) = g;
            }
        }
    }
}

extern "C" void kernel_launch(void* const* d_in, const int* in_sizes, int n_in,
                              void* d_out, int out_size, void* d_ws, size_t ws_size,
                              hipStream_t stream) {
    const float* x       = (const float*)d_in[0];
    const int*   ei      = (const int*)d_in[1];
    const float* deg_inv = (const float*)d_in[2];
    const float* W       = (const float*)d_in[3];
    const float* bias    = (const float*)d_in[4];
    float*       out     = (float*)d_out;

    const int* src = ei;
    const int* dst = ei + N_EDGES;

    // ws layout: mb | counts | state(128) | incl | cursor | csr | Wb | xb
    unsigned short* mb = (unsigned short*)d_ws;
    size_t mb_bytes = (size_t)N_NODES * DIM_IN * sizeof(unsigned short);   // 25.6 MB
    int*      counts = (int*)((char*)d_ws + mb_bytes);
    unsigned* state  = (unsigned*)(counts + N_NODES);
    int*      incl   = (int*)(state + 128);
    int*      cursor = incl + N_NODES;
    int*      csr    = cursor + N_NODES;
    unsigned short* Wb = (unsigned short*)(csr + N_EDGES);
    unsigned short* xb = Wb + DIM_IN * DIM_OUT;

    k_zero<<<SCAN_NB, 1024, 0, stream>>>(counts);   // counts + state
    k_prep<<<(N_NODES * DIM_IN / 4) / 256, 256, 0, stream>>>(x, W, dst, xb, Wb, counts);
    k_scan<<<SCAN_NB, 1024, 0, stream>>>(counts, incl, cursor, state);
    k_fill<<<N_EDGES / 256, 256, 0, stream>>>(src, dst, cursor, csr);
    k_agg <<<N_NODES / 4, 256, 0, stream>>>(xb, csr, incl, counts, deg_inv, mb);
    k_gemm<<<(N_NODES + NPB - 1) / NPB, 512, 0, stream>>>(mb, Wb, bias, out);
}